// Round 6
// baseline (356.104 us; speedup 1.0000x reference)
//
#include <hip/hip_runtime.h>
#include <hip/hip_bf16.h>
#include <stdint.h>

#define IN_F   4096
#define OUT_F  4096
#define BATCHN 8192

#define BK   64
#define NTK  (IN_F / BK)       // 64 K-tiles
#define HOFF (128 * IN_F)      // half-tile (128 rows) offset in elements

using f32x4 = __attribute__((ext_vector_type(4))) float;
using f16x8 = __attribute__((ext_vector_type(8))) _Float16;
using i32x4 = __attribute__((ext_vector_type(4))) int;
using u32x4 = __attribute__((ext_vector_type(4))) unsigned int;

__device__ __forceinline__ void stg(const _Float16* src, int kelem, char* sm, int dstoff) {
    __builtin_amdgcn_global_load_lds(
        (const __attribute__((address_space(1))) void*)(src + kelem),
        (__attribute__((address_space(3))) void*)(sm + dstoff), 16, 0, 0);
}

__device__ __forceinline__ u32x4 pack8_f16(const float* v) {
    union { _Float16 h[8]; u32x4 u; } p;
#pragma unroll
    for (int i = 0; i < 8; ++i) p.h[i] = (_Float16)v[i];
    return p.u;
}

// ---------------------------------------------------------------------------
// Fused prep: blocks [0,8192): build W (fp16); [8192,24576): convert x;
// [24576,24592): bias.
// ---------------------------------------------------------------------------
__global__ __launch_bounds__(256) void prep(const float* __restrict__ hw,
                                            const float* __restrict__ xiW,
                                            const int*   __restrict__ idxW,
                                            u32x4* __restrict__ Wh,
                                            const float* __restrict__ x,
                                            u32x4* __restrict__ Xh,
                                            const float* __restrict__ hb,
                                            const float* __restrict__ xiB,
                                            const int*   __restrict__ idxB,
                                            float* __restrict__ bias) {
    const int b = blockIdx.x;
    if (b < 8192) {
        size_t t = (size_t)b * 256 + threadIdx.x;
        size_t base = t * 8;
        i32x4 i0 = *(const i32x4*)(idxW + base);
        i32x4 i1 = *(const i32x4*)(idxW + base + 4);
        f32x4 s0 = *(const f32x4*)(xiW + base);
        f32x4 s1 = *(const f32x4*)(xiW + base + 4);
        float v[8];
        v[0] = hw[i0[0]] * s0[0];
        v[1] = hw[i0[1]] * s0[1];
        v[2] = hw[i0[2]] * s0[2];
        v[3] = hw[i0[3]] * s0[3];
        v[4] = hw[i1[0]] * s1[0];
        v[5] = hw[i1[1]] * s1[1];
        v[6] = hw[i1[2]] * s1[2];
        v[7] = hw[i1[3]] * s1[3];
        Wh[t] = pack8_f16(v);
    } else if (b < 24576) {
        size_t t = (size_t)(b - 8192) * 256 + threadIdx.x;
        size_t base = t * 8;
        f32x4 a = *(const f32x4*)(x + base);
        f32x4 c = *(const f32x4*)(x + base + 4);
        float v[8] = {a[0], a[1], a[2], a[3], c[0], c[1], c[2], c[3]};
        Xh[t] = pack8_f16(v);
    } else {
        int o = (b - 24576) * 256 + threadIdx.x;
        if (o < OUT_F) bias[o] = hb[idxB[o]] * xiB[o];
    }
}

// ---------------------------------------------------------------------------
// 256x256x64 GEMM, fp16 MFMA, fp32 out + bias.  TWO barriers per K-tile.
// Per tile T (cur = buf[T&1]; stages target T+2 -> same cur buffer):
//   [alpha barrier]  (entering: T's buffer landed via prev vmcnt(8)+barrier)
//   region 1: rd ALL 24 frags (aFlo,bF01 first) | MFMA Q00+Q01 (32)
//             s_waitcnt lgkmcnt(0)   (all cur reads complete -> WAR ready)
//   [beta barrier]
//   region 2: stg 8 (T+2, cur) | MFMA Q10+Q11 (32) | vmcnt(8)
// FIFO: entering tile T outstanding = T+1's 8; region2 adds T+2's 8 (=16);
// vmcnt(8) retires exactly T+1's 8 before T+1's alpha. Prologue stages
// T0+T1, vmcnt(8) lands T0. Tail: tile 62 no-stage vmcnt(0); tile 63 bare.
// Swizzle: phys = linear ^ ((row&7)<<4), inverse on global src, fwd on reads.
// ---------------------------------------------------------------------------
__global__ __launch_bounds__(512, 2) void gemm_2b(const _Float16* __restrict__ A,
                                                  const _Float16* __restrict__ Bm,
                                                  const float*    __restrict__ bias,
                                                  float*          __restrict__ C) {
    extern __shared__ char smem[];
    const int tid  = threadIdx.x;
    const int lane = tid & 63;
    const int wave = tid >> 6;
    const int wr   = wave >> 2;
    const int wc   = wave & 3;

    const int bid   = blockIdx.x;
    const int xcd   = bid & 7;
    const int local = bid >> 3;
    const int m_idx = (xcd & 3) * 8 + (local & 7);
    const int n_idx = (xcd >> 2) * 8 + (local >> 3);
    const size_t brow = (size_t)m_idx * 256;
    const size_t bcol = (size_t)n_idx * 256;

    const int srow = tid >> 3;
    const int scol = ((tid & 7) ^ (srow & 7)) << 3;
    const _Float16* aS0 = A  + (brow + srow)      * IN_F + scol;
    const _Float16* aS1 = A  + (brow + 64 + srow) * IN_F + scol;
    const _Float16* bS0 = Bm + (bcol + srow)      * IN_F + scol;
    const _Float16* bS1 = Bm + (bcol + 64 + srow) * IN_F + scol;
    const _Float16* aS0h = aS0 + HOFF;
    const _Float16* aS1h = aS1 + HOFF;
    const _Float16* bS0h = bS0 + HOFF;
    const _Float16* bS1h = bS1 + HOFF;
    const int dA = tid << 4;
    const int dB = 32768 + (tid << 4);

    const int rrow = lane & 15;
    const int pc0  = (((lane >> 4))     ^ (lane & 7)) << 4;
    const int pc1  = ((4 + (lane >> 4)) ^ (lane & 7)) << 4;
    const int aAd0 = (wr * 128 + rrow) * 128 + pc0;
    const int aAd1 = (wr * 128 + rrow) * 128 + pc1;
    const int bAd0 = 32768 + (wc * 64 + rrow) * 128 + pc0;
    const int bAd1 = 32768 + (wc * 64 + rrow) * 128 + pc1;

    f32x4 acc[8][4];
#pragma unroll
    for (int m = 0; m < 8; ++m)
#pragma unroll
        for (int n = 0; n < 4; ++n) acc[m][n] = (f32x4){0.f, 0.f, 0.f, 0.f};

    f16x8 aFlo[4][2], aFhi[4][2], bF[4][2];

#define SB() __builtin_amdgcn_sched_barrier(0)

#define MQ(M0, N0, AF) do { \
    _Pragma("unroll") \
    for (int ks = 0; ks < 2; ++ks) { \
        _Pragma("unroll") \
        for (int i = 0; i < 4; ++i) { \
            _Pragma("unroll") \
            for (int nn = 0; nn < 2; ++nn) \
                acc[(M0) + i][(N0) + nn] = __builtin_amdgcn_mfma_f32_16x16x32_f16( \
                    AF[i][ks], bF[(N0) + nn][ks], acc[(M0) + i][(N0) + nn], 0, 0, 0); \
        } } } while (0)

#define GTILE(CURB, KO, STGON, VM) { \
    const int AC0 = aAd0 + (CURB), AC1 = aAd1 + (CURB); \
    const int BC0 = bAd0 + (CURB), BC1 = bAd1 + (CURB); \
    /* alpha */ \
    __builtin_amdgcn_s_barrier(); SB(); \
    /* region 1: all reads; Q00 operands first */ \
    aFlo[0][0] = *(const f16x8*)(smem + AC0); \
    aFlo[1][0] = *(const f16x8*)(smem + AC0 + 2048); \
    aFlo[2][0] = *(const f16x8*)(smem + AC0 + 4096); \
    aFlo[3][0] = *(const f16x8*)(smem + AC0 + 6144); \
    bF[0][0] = *(const f16x8*)(smem + BC0); \
    bF[1][0] = *(const f16x8*)(smem + BC0 + 2048); \
    aFlo[0][1] = *(const f16x8*)(smem + AC1); \
    aFlo[1][1] = *(const f16x8*)(smem + AC1 + 2048); \
    aFlo[2][1] = *(const f16x8*)(smem + AC1 + 4096); \
    aFlo[3][1] = *(const f16x8*)(smem + AC1 + 6144); \
    bF[0][1] = *(const f16x8*)(smem + BC1); \
    bF[1][1] = *(const f16x8*)(smem + BC1 + 2048); \
    bF[2][0] = *(const f16x8*)(smem + BC0 + 4096); \
    bF[3][0] = *(const f16x8*)(smem + BC0 + 6144); \
    bF[2][1] = *(const f16x8*)(smem + BC1 + 4096); \
    bF[3][1] = *(const f16x8*)(smem + BC1 + 6144); \
    aFhi[0][0] = *(const f16x8*)(smem + AC0 + 8192); \
    aFhi[1][0] = *(const f16x8*)(smem + AC0 + 10240); \
    aFhi[2][0] = *(const f16x8*)(smem + AC0 + 12288); \
    aFhi[3][0] = *(const f16x8*)(smem + AC0 + 14336); \
    aFhi[0][1] = *(const f16x8*)(smem + AC1 + 8192); \
    aFhi[1][1] = *(const f16x8*)(smem + AC1 + 10240); \
    aFhi[2][1] = *(const f16x8*)(smem + AC1 + 12288); \
    aFhi[3][1] = *(const f16x8*)(smem + AC1 + 14336); \
    __builtin_amdgcn_s_setprio(1); \
    MQ(0, 0, aFlo); \
    MQ(0, 2, aFlo); \
    __builtin_amdgcn_s_setprio(0); \
    asm volatile("s_waitcnt lgkmcnt(0)" ::: "memory"); SB(); \
    /* beta */ \
    __builtin_amdgcn_s_barrier(); SB(); \
    /* region 2: stages first (issue-and-forget), then MFMA, then vmcnt */ \
    if (STGON) { \
        stg(bS0,  KO, smem, (CURB) + dB); \
        stg(bS1,  KO, smem, (CURB) + dB + 8192); \
        stg(bS0h, KO, smem, (CURB) + dB + 16384); \
        stg(bS1h, KO, smem, (CURB) + dB + 16384 + 8192); \
        stg(aS0,  KO, smem, (CURB) + dA); \
        stg(aS1,  KO, smem, (CURB) + dA + 8192); \
        stg(aS0h, KO, smem, (CURB) + dA + 16384); \
        stg(aS1h, KO, smem, (CURB) + dA + 16384 + 8192); \
    } \
    __builtin_amdgcn_s_setprio(1); \
    MQ(4, 0, aFhi); \
    MQ(4, 2, aFhi); \
    __builtin_amdgcn_s_setprio(0); \
    if ((VM) == 8) { asm volatile("s_waitcnt vmcnt(8)" ::: "memory"); } \
    else if ((VM) == 0) { asm volatile("s_waitcnt vmcnt(0)" ::: "memory"); } \
    SB(); \
}

    // --- prologue: stage T0 (buf0) + T1 (buf1); land T0; keep T1 in flight
    stg(aS0, 0, smem, dA);
    stg(aS1, 0, smem, dA + 8192);
    stg(aS0h, 0, smem, dA + 16384);
    stg(aS1h, 0, smem, dA + 16384 + 8192);
    stg(bS0, 0, smem, dB);
    stg(bS1, 0, smem, dB + 8192);
    stg(bS0h, 0, smem, dB + 16384);
    stg(bS1h, 0, smem, dB + 16384 + 8192);
    stg(bS0, 64, smem, 65536 + dB);
    stg(bS1, 64, smem, 65536 + dB + 8192);
    stg(bS0h, 64, smem, 65536 + dB + 16384);
    stg(bS1h, 64, smem, 65536 + dB + 16384 + 8192);
    stg(aS0, 64, smem, 65536 + dA);
    stg(aS1, 64, smem, 65536 + dA + 8192);
    stg(aS0h, 64, smem, 65536 + dA + 16384);
    stg(aS1h, 64, smem, 65536 + dA + 16384 + 8192);
    asm volatile("s_waitcnt vmcnt(8)" ::: "memory");   // T0 landed; T1 (8) in flight
    SB();

    // --- main loop: tiles 0..61, unroll 2 (buf0 then buf1), full staging
    for (int kt = 0; kt < NTK - 2; kt += 2) {
        GTILE(0,     128, 1, 8);
        GTILE(65536, 192, 1, 8);
        aS0 += 128; aS1 += 128; bS0 += 128; bS1 += 128;
        aS0h += 128; aS1h += 128; bS0h += 128; bS1h += 128;
    }
    // --- tail: tile 62 (no stages, full drain), tile 63 (compute only)
    GTILE(0,     0, 0, 0);
    GTILE(65536, 0, 0, -1);

#undef GTILE
#undef MQ
#undef SB

    // --- epilogue: C/D layout col = lane&15, row = (lane>>4)*4 + j ---
    const int crow = (lane >> 4) << 2;
    const int ccol = lane & 15;
#pragma unroll
    for (int n = 0; n < 4; ++n) {
        const size_t col = bcol + wc * 64 + n * 16 + ccol;
        const float bv = bias[col];
#pragma unroll
        for (int m = 0; m < 8; ++m) {
            const size_t row = brow + wr * 128 + m * 16 + crow;
            float* cp = C + row * OUT_F + col;
#pragma unroll
            for (int j = 0; j < 4; ++j)
                cp[(size_t)j * OUT_F] = acc[m][n][j] + bv;
        }
    }
}

// ---------------------------------------------------------------------------
extern "C" void kernel_launch(void* const* d_in, const int* in_sizes, int n_in,
                              void* d_out, int out_size, void* d_ws, size_t ws_size,
                              hipStream_t stream) {
    const float* x    = (const float*)d_in[0];
    const float* hw   = (const float*)d_in[1];
    const float* hb   = (const float*)d_in[2];
    const float* xiW  = (const float*)d_in[3];
    const float* xiB  = (const float*)d_in[4];
    const int*   idxW = (const int*)d_in[5];
    const int*   idxB = (const int*)d_in[6];
    float* out = (float*)d_out;

    char* ws = (char*)d_ws;
    _Float16* Wh  = (_Float16*)ws;                                   // 32 MB
    _Float16* Xh  = (_Float16*)(ws + (size_t)32 * 1024 * 1024);      // 64 MB
    float*    bia = (float*)   (ws + (size_t)96 * 1024 * 1024);      // 16 KB

    (void)hipFuncSetAttribute((const void*)gemm_2b,
                              hipFuncAttributeMaxDynamicSharedMemorySize, 131072);

    prep<<<24592, 256, 0, stream>>>(hw, xiW, idxW, (u32x4*)Wh,
                                    x, (u32x4*)Xh, hb, xiB, idxB, bia);
    gemm_2b<<<512, 512, 131072, stream>>>(Xh, Wh, bia, out);
}

// Round 7
// 281.963 us; speedup vs baseline: 1.2629x; 1.2629x over previous
//
#include <hip/hip_runtime.h>
#include <stdint.h>

#define IN_F   4096
#define OUT_F  4096
#define BATCHN 8192
#define BK     64
#define NTK    (IN_F / BK)   // 64 K-tiles

using f32x4 = __attribute__((ext_vector_type(4))) float;
using i32x4 = __attribute__((ext_vector_type(4))) int;
using u32x2 = __attribute__((ext_vector_type(2))) unsigned int;
using u32x4 = __attribute__((ext_vector_type(4))) unsigned int;

__device__ __forceinline__ void stg(const int8_t* src, char* sm, int dstoff) {
    __builtin_amdgcn_global_load_lds(
        (const __attribute__((address_space(1))) void*)src,
        (__attribute__((address_space(3))) void*)(sm + dstoff), 16, 0, 0);
}

__device__ __forceinline__ unsigned pack4(int a, int b, int c, int d) {
    return (unsigned)(a & 255) | ((unsigned)(b & 255) << 8) |
           ((unsigned)(c & 255) << 16) | ((unsigned)(d & 255) << 24);
}
__device__ __forceinline__ int q8(float v, float s) {
    int q = __float2int_rn(v * s);
    return q > 127 ? 127 : (q < -127 ? -127 : q);
}

// ---------------------------------------------------------------------------
// Fused prep:
//  blocks [0,8192):      W quant  wq = round(hw[idx]*xi*8128)  -> i8 [4096][4096]
//  blocks [8192,16384):  x row quant (one block per row): rowmax -> scale
//                        xq = round(x*127/rowmax) -> i8 [8192][4096]; rowmul
//  blocks [16384,16400): bias
// ---------------------------------------------------------------------------
__global__ __launch_bounds__(256) void prep(const float* __restrict__ hw,
                                            const float* __restrict__ xiW,
                                            const int*   __restrict__ idxW,
                                            u32x2* __restrict__ Wq,
                                            const float* __restrict__ x,
                                            u32x4* __restrict__ Xq,
                                            float* __restrict__ rowmul,
                                            const float* __restrict__ hb,
                                            const float* __restrict__ xiB,
                                            const int*   __restrict__ idxB,
                                            float* __restrict__ bias) {
    __shared__ float wm[4];
    const int b   = blockIdx.x;
    const int tid = threadIdx.x;
    if (b < 8192) {
        size_t t = (size_t)b * 256 + tid;
        size_t base = t * 8;
        i32x4 i0 = *(const i32x4*)(idxW + base);
        i32x4 i1 = *(const i32x4*)(idxW + base + 4);
        f32x4 s0 = *(const f32x4*)(xiW + base);
        f32x4 s1 = *(const f32x4*)(xiW + base + 4);
        const float SW = 8128.0f;  // 127*64; |W| < 1/64 exactly -> fits i8
        int a0 = q8(hw[i0[0]] * s0[0], SW);
        int a1 = q8(hw[i0[1]] * s0[1], SW);
        int a2 = q8(hw[i0[2]] * s0[2], SW);
        int a3 = q8(hw[i0[3]] * s0[3], SW);
        int a4 = q8(hw[i1[0]] * s1[0], SW);
        int a5 = q8(hw[i1[1]] * s1[1], SW);
        int a6 = q8(hw[i1[2]] * s1[2], SW);
        int a7 = q8(hw[i1[3]] * s1[3], SW);
        u32x2 o;
        o[0] = pack4(a0, a1, a2, a3);
        o[1] = pack4(a4, a5, a6, a7);
        Wq[t] = o;
    } else if (b < 16384) {
        const int row = b - 8192;
        const float* xr = x + (size_t)row * IN_F + tid * 16;
        f32x4 v0 = *(const f32x4*)(xr);
        f32x4 v1 = *(const f32x4*)(xr + 4);
        f32x4 v2 = *(const f32x4*)(xr + 8);
        f32x4 v3 = *(const f32x4*)(xr + 12);
        float mx = 0.f;
#pragma unroll
        for (int j = 0; j < 4; ++j) {
            mx = fmaxf(mx, fmaxf(fabsf(v0[j]), fabsf(v1[j])));
            mx = fmaxf(mx, fmaxf(fabsf(v2[j]), fabsf(v3[j])));
        }
#pragma unroll
        for (int m = 32; m >= 1; m >>= 1) mx = fmaxf(mx, __shfl_xor(mx, m));
        if ((tid & 63) == 0) wm[tid >> 6] = mx;
        __syncthreads();
        mx = fmaxf(fmaxf(wm[0], wm[1]), fmaxf(wm[2], wm[3]));
        mx = fmaxf(mx, 1e-8f);
        const float s = 127.0f / mx;
        u32x4 o;
        o[0] = pack4(q8(v0[0], s), q8(v0[1], s), q8(v0[2], s), q8(v0[3], s));
        o[1] = pack4(q8(v1[0], s), q8(v1[1], s), q8(v1[2], s), q8(v1[3], s));
        o[2] = pack4(q8(v2[0], s), q8(v2[1], s), q8(v2[2], s), q8(v2[3], s));
        o[3] = pack4(q8(v3[0], s), q8(v3[1], s), q8(v3[2], s), q8(v3[3], s));
        Xq[(size_t)row * 256 + tid] = o;
        if (tid == 0) rowmul[row] = mx / (127.0f * 8128.0f);
    } else {
        int o = (b - 16384) * 256 + tid;
        if (o < OUT_F) bias[o] = hb[idxB[o]] * xiB[o];
    }
}

// ---------------------------------------------------------------------------
// i8 GEMM: 128x128 tile, BK=64, 256 threads (4 waves, 2x2 of 64x64),
// mfma_i32_16x16x64_i8, 2-buffer LDS (32 KiB) -> 4 blocks/CU of TLP.
// Per tile: rd 8 frags (cur) | stage 4 -> nxt | 16 MFMA | lgkm+vmcnt(0) | bar.
// LDS swizzle: 64B rows, chunk c -> c ^ (row&3) (inverse on global source,
// forward on ds_read; gload_lds dest stays linear). Residual 4-way conflict
// on reads accepted (light path). Epilogue: f32 = acc * rowmul[row] + bias.
// ---------------------------------------------------------------------------
__global__ __launch_bounds__(256, 4) void gemm_i8(const int8_t* __restrict__ Aq, // [8192][4096]
                                                  const int8_t* __restrict__ Bq, // [4096][4096]
                                                  const float*  __restrict__ rowmul,
                                                  const float*  __restrict__ bias,
                                                  float*        __restrict__ C) {
    __shared__ char smem[32768];
    const int tid  = threadIdx.x;
    const int lane = tid & 63;
    const int wave = tid >> 6;
    const int wr   = wave >> 1;  // 0..1 -> rows wr*64
    const int wc   = wave & 1;   // 0..1 -> cols wc*64

    // XCD chunking: 2048 blocks; each XCD owns a 16m x 16n tile region.
    const int bid   = blockIdx.x;
    const int xcd   = bid & 7;
    const int local = bid >> 3;                       // 0..255
    const int m_idx = (xcd & 3) * 16 + (local & 15);  // 0..63
    const int n_idx = (xcd >> 2) * 16 + (local >> 4); // 0..31
    const size_t brow = (size_t)m_idx * 128;
    const size_t bcol = (size_t)n_idx * 128;

    // staging: thread t -> row r0 = t>>2 (0..63), chunk c = t&3 (16B chunks);
    // source chunk inverse-swizzled: c ^ (r0&3). Dest linear t*16.
    const int r0 = tid >> 2;
    const int sc = ((tid & 3) ^ (r0 & 3)) << 4;
    const int8_t* aSrc0 = Aq + (size_t)(brow + r0)      * IN_F + sc;
    const int8_t* aSrc1 = Aq + (size_t)(brow + 64 + r0) * IN_F + sc;
    const int8_t* bSrc0 = Bq + (size_t)(bcol + r0)      * IN_F + sc;
    const int8_t* bSrc1 = Bq + (size_t)(bcol + 64 + r0) * IN_F + sc;
    const int dA0 = tid << 4;
    const int dA1 = (tid << 4) + 4096;
    const int dB0 = 8192 + (tid << 4);
    const int dB1 = 12288 + (tid << 4);

    // ds_read addrs (forward swizzle): frag m at aRd + m*1024, n at bRd + n*1024
    const int rrow = lane & 15;
    const int pcc  = (((lane >> 4)) ^ (rrow & 3)) << 4;
    const int aRd  = (wr * 64 + rrow) * 64 + pcc;
    const int bRd  = 8192 + (wc * 64 + rrow) * 64 + pcc;

    i32x4 acc[4][4];
#pragma unroll
    for (int m = 0; m < 4; ++m)
#pragma unroll
        for (int n = 0; n < 4; ++n) acc[m][n] = (i32x4){0, 0, 0, 0};

    i32x4 aF[4], bF[4];

#define TILE(CURB, NXTB, KOFF, STGON) { \
    aF[0] = *(const i32x4*)(smem + (CURB) + aRd); \
    aF[1] = *(const i32x4*)(smem + (CURB) + aRd + 1024); \
    aF[2] = *(const i32x4*)(smem + (CURB) + aRd + 2048); \
    aF[3] = *(const i32x4*)(smem + (CURB) + aRd + 3072); \
    bF[0] = *(const i32x4*)(smem + (CURB) + bRd); \
    bF[1] = *(const i32x4*)(smem + (CURB) + bRd + 1024); \
    bF[2] = *(const i32x4*)(smem + (CURB) + bRd + 2048); \
    bF[3] = *(const i32x4*)(smem + (CURB) + bRd + 3072); \
    if (STGON) { \
        stg(aSrc0 + (KOFF), smem, (NXTB) + dA0); \
        stg(aSrc1 + (KOFF), smem, (NXTB) + dA1); \
        stg(bSrc0 + (KOFF), smem, (NXTB) + dB0); \
        stg(bSrc1 + (KOFF), smem, (NXTB) + dB1); \
    } \
    __builtin_amdgcn_s_setprio(1); \
    _Pragma("unroll") \
    for (int m = 0; m < 4; ++m) { \
        _Pragma("unroll") \
        for (int n = 0; n < 4; ++n) \
            acc[m][n] = __builtin_amdgcn_mfma_i32_16x16x64_i8( \
                aF[m], bF[n], acc[m][n], 0, 0, 0); \
    } \
    __builtin_amdgcn_s_setprio(0); \
    asm volatile("s_waitcnt lgkmcnt(0) vmcnt(0)" ::: "memory"); \
    __builtin_amdgcn_sched_barrier(0); \
    __builtin_amdgcn_s_barrier(); \
    __builtin_amdgcn_sched_barrier(0); \
}

    // prologue: stage T0 into buf0, land it
    stg(aSrc0, smem, dA0);
    stg(aSrc1, smem, dA1);
    stg(bSrc0, smem, dB0);
    stg(bSrc1, smem, dB1);
    asm volatile("s_waitcnt vmcnt(0)" ::: "memory");
    __builtin_amdgcn_sched_barrier(0);
    __builtin_amdgcn_s_barrier();
    __builtin_amdgcn_sched_barrier(0);

    // main loop: unroll 2 (buf0, buf1); tile kt stages kt+1 into other buf
    for (int kt = 0; kt < NTK; kt += 2) {
        TILE(0, 16384, 64, 1);                    // tile kt   (stages kt+1)
        TILE(16384, 0, 128, (kt < NTK - 2));      // tile kt+1 (stages kt+2)
        aSrc0 += 128; aSrc1 += 128; bSrc0 += 128; bSrc1 += 128;
    }
#undef TILE

    // epilogue: C/D col = lane&15, row = (lane>>4)*4 + j (shape-determined)
    const int crow = (lane >> 4) << 2;
    const int ccol = lane & 15;
#pragma unroll
    for (int m = 0; m < 4; ++m) {
        const size_t rowbase = brow + wr * 64 + m * 16 + crow;
        float rm[4];
#pragma unroll
        for (int j = 0; j < 4; ++j) rm[j] = rowmul[rowbase + j];
#pragma unroll
        for (int n = 0; n < 4; ++n) {
            const size_t col = bcol + wc * 64 + n * 16 + ccol;
            const float bv = bias[col];
            float* cp = C + rowbase * OUT_F + col;
#pragma unroll
            for (int j = 0; j < 4; ++j)
                cp[(size_t)j * OUT_F] = (float)acc[m][n][j] * rm[j] + bv;
        }
    }
}

// ---------------------------------------------------------------------------
extern "C" void kernel_launch(void* const* d_in, const int* in_sizes, int n_in,
                              void* d_out, int out_size, void* d_ws, size_t ws_size,
                              hipStream_t stream) {
    const float* x    = (const float*)d_in[0];
    const float* hw   = (const float*)d_in[1];
    const float* hb   = (const float*)d_in[2];
    const float* xiW  = (const float*)d_in[3];
    const float* xiB  = (const float*)d_in[4];
    const int*   idxW = (const int*)d_in[5];
    const int*   idxB = (const int*)d_in[6];
    float* out = (float*)d_out;

    char* ws = (char*)d_ws;
    int8_t* Wq     = (int8_t*)ws;                                   // 16 MB
    int8_t* Xq     = (int8_t*)(ws + (size_t)16 * 1024 * 1024);      // 32 MB
    float*  rowmul = (float*)(ws + (size_t)48 * 1024 * 1024);       // 32 KB
    float*  bia    = (float*)(ws + (size_t)49 * 1024 * 1024);       // 16 KB

    // 8192 (W) + 8192 (x rows) + 16 (bias) blocks
    prep<<<16400, 256, 0, stream>>>(hw, xiW, idxW, (u32x2*)Wq,
                                    x, (u32x4*)Xq, rowmul,
                                    hb, xiB, idxB, bia);
    // 64 x 32 tiles = 2048 blocks, 256 threads
    gemm_i8<<<2048, 256, 0, stream>>>(Xq, Wq, rowmul, bia, out);
}